// Round 1
// baseline (21.734 us; speedup 1.0000x reference)
//
#include <hip/hip_runtime.h>

#define FDIM 1024
#define NBINS 64
#define NB 63            // number of boundaries
#define WAVES_PER_BLOCK 4
#define SUBHIST 4        // one sub-histogram per 16-lane group

__global__ __launch_bounds__(256) void dist_tok_kernel(
    const float* __restrict__ x, const float* __restrict__ bnd,
    float* __restrict__ out, int nrows)
{
    __shared__ float s_bnd[NB];
    __shared__ unsigned int s_hist[WAVES_PER_BLOCK][SUBHIST][NBINS];

    const int tid  = threadIdx.x;
    const int wave = tid >> 6;
    const int lane = tid & 63;
    const int grp  = lane >> 4;

    if (tid < NB) s_bnd[tid] = bnd[tid];

    // zero this wave's 4 sub-histograms (4*64 u32, 64 lanes x 4 each)
    #pragma unroll
    for (int i = 0; i < SUBHIST; ++i)
        s_hist[wave][i][lane] = 0u;

    __syncthreads();  // s_bnd written by wave 0 only, read by all waves

    const int row = blockIdx.x * WAVES_PER_BLOCK + wave;
    if (row < nrows) {
        const float4* xr = (const float4*)(x + (size_t)row * FDIM);
        const float inv_h = 62.0f / 8.0f;   // 1/step for linspace(-4,4,63)
        #pragma unroll
        for (int c = 0; c < 4; ++c) {
            // wave-contiguous 1KiB load: lanes cover elements [c*256, c*256+256)
            float4 v = xr[c * 64 + lane];
            float vals[4] = {v.x, v.y, v.z, v.w};
            #pragma unroll
            for (int e = 0; e < 4; ++e) {
                float xv = vals[e];
                // analytic guess for count of boundaries <= xv
                int j = (int)floorf((xv + 4.0f) * inv_h) + 1;
                j = j < 0 ? 0 : (j > NB ? NB : j);
                // exact fixup vs actual boundary values (handles fp rounding
                // and exact ties with side='right' semantics). 0-1 iters typ.
                while (j < NB && s_bnd[j] <= xv) ++j;
                while (j > 0 && s_bnd[j - 1] > xv) --j;
                atomicAdd(&s_hist[wave][grp][j], 1u);
            }
        }
    }

    __syncthreads();  // cheap; orders per-wave LDS atomics before merge reads

    if (row < nrows) {
        unsigned int total = s_hist[wave][0][lane] + s_hist[wave][1][lane]
                           + s_hist[wave][2][lane] + s_hist[wave][3][lane];
        out[(size_t)row * NBINS + lane] = (float)total * (1.0f / (float)FDIM);
    }
}

extern "C" void kernel_launch(void* const* d_in, const int* in_sizes, int n_in,
                              void* d_out, int out_size, void* d_ws, size_t ws_size,
                              hipStream_t stream) {
    const float* x   = (const float*)d_in[0];
    const float* bnd = (const float*)d_in[1];
    float* out = (float*)d_out;

    const int nrows = in_sizes[0] / FDIM;               // 16384
    const int grid  = (nrows + WAVES_PER_BLOCK - 1) / WAVES_PER_BLOCK;  // 4096

    dist_tok_kernel<<<grid, 256, 0, stream>>>(x, bnd, out, nrows);
}

// Round 2
// 17.865 us; speedup vs baseline: 1.2166x; 1.2166x over previous
//
#include <hip/hip_runtime.h>
#include <math.h>

#define FDIM 1024
#define NBINS 64
#define NB 63            // number of boundaries
#define WAVES_PER_BLOCK 4
#define SUBHIST 4        // one sub-histogram per 16-lane group

__global__ __launch_bounds__(256) void dist_tok_kernel(
    const float* __restrict__ x, const float* __restrict__ bnd,
    float* __restrict__ out, int nrows)
{
    // padded boundaries: s_bndp[0] = -inf, s_bndp[1..63] = bnd[0..62], s_bndp[64] = +inf
    __shared__ float s_bndp[NB + 2];
    __shared__ unsigned int s_hist[WAVES_PER_BLOCK][SUBHIST][NBINS];

    const int tid  = threadIdx.x;
    const int wave = tid >> 6;
    const int lane = tid & 63;
    const int grp  = lane >> 4;        // 16-lane group id, 0..3
    const int gx   = grp << 3;         // bank-stagger XOR constant: 0,8,16,24

    if (tid < NB) s_bndp[tid + 1] = bnd[tid];
    if (tid == NB) { s_bndp[0] = -INFINITY; s_bndp[NB + 1] = INFINITY; }

    #pragma unroll
    for (int i = 0; i < SUBHIST; ++i)
        s_hist[wave][i][lane] = 0u;

    __syncthreads();

    const int row = blockIdx.x * WAVES_PER_BLOCK + wave;
    if (row < nrows) {
        const float4* xr = (const float4*)(x + (size_t)row * FDIM);
        // issue all 4 coalesced 1KiB wave-loads up front
        float4 v0 = xr[lane];
        float4 v1 = xr[64 + lane];
        float4 v2 = xr[128 + lane];
        float4 v3 = xr[192 + lane];

        float vals[16] = {v0.x, v0.y, v0.z, v0.w, v1.x, v1.y, v1.z, v1.w,
                          v2.x, v2.y, v2.z, v2.w, v3.x, v3.y, v3.z, v3.w};
        #pragma unroll
        for (int e = 0; e < 16; ++e) {
            float xv = vals[e];
            // analytic guess: bin ~= trunc(7.75*x + 32); fixup makes it exact
            int j = (int)fmaf(xv, 7.75f, 32.0f);
            j = j < 0 ? 0 : (j > NB ? NB : j);
            // verify with one adjacent-pair LDS read (ds_read2_b32)
            float lo = s_bndp[j];
            float hi = s_bndp[j + 1];
            if (__builtin_expect(!(lo <= xv && xv < hi), 0)) {
                // rare exact fixup (fp rounding near a boundary / exact ties)
                while (s_bndp[j + 1] <= xv) ++j;   // +inf sentinel terminates
                while (s_bndp[j] > xv) --j;        // -inf sentinel terminates
            }
            atomicAdd(&s_hist[wave][grp][j ^ gx], 1u);
        }
    }

    __syncthreads();

    if (row < nrows) {
        // un-stagger while merging: group g stored bin l at l ^ (8g)
        unsigned int total = s_hist[wave][0][lane]
                           + s_hist[wave][1][lane ^ 8]
                           + s_hist[wave][2][lane ^ 16]
                           + s_hist[wave][3][lane ^ 24];
        out[(size_t)row * NBINS + lane] = (float)total * (1.0f / (float)FDIM);
    }
}

extern "C" void kernel_launch(void* const* d_in, const int* in_sizes, int n_in,
                              void* d_out, int out_size, void* d_ws, size_t ws_size,
                              hipStream_t stream) {
    const float* x   = (const float*)d_in[0];
    const float* bnd = (const float*)d_in[1];
    float* out = (float*)d_out;

    const int nrows = in_sizes[0] / FDIM;               // 16384
    const int grid  = (nrows + WAVES_PER_BLOCK - 1) / WAVES_PER_BLOCK;  // 4096

    dist_tok_kernel<<<grid, 256, 0, stream>>>(x, bnd, out, nrows);
}

// Round 3
// 17.600 us; speedup vs baseline: 1.2349x; 1.0150x over previous
//
#include <hip/hip_runtime.h>
#include <math.h>

#define FDIM 1024
#define NBINS 64
#define NB 63            // number of boundaries
#define WAVES_PER_BLOCK 4
#define SUBHIST 8        // one sub-histogram per 8-lane group
#define EPS 1e-4f        // frac-space guard band for analytic binning

__global__ __launch_bounds__(256) void dist_tok_kernel(
    const float* __restrict__ x, const float* __restrict__ bnd,
    float* __restrict__ out, int nrows)
{
    // padded boundaries: s_bndp[0] = -inf, s_bndp[1..63] = bnd[0..62], s_bndp[64] = +inf
    __shared__ float s_bndp[NB + 2];
    __shared__ unsigned int s_hist[WAVES_PER_BLOCK][SUBHIST][NBINS];

    const int tid  = threadIdx.x;
    const int wave = tid >> 6;
    const int lane = tid & 63;
    const int grp  = lane >> 3;        // 8-lane group id, 0..7
    const int gx   = grp << 2;         // bank-stagger XOR: 0,4,...,28

    if (tid < NB) s_bndp[tid + 1] = bnd[tid];
    if (tid == NB) { s_bndp[0] = -INFINITY; s_bndp[NB + 1] = INFINITY; }

    #pragma unroll
    for (int i = 0; i < SUBHIST; ++i)
        s_hist[wave][i][lane] = 0u;

    __syncthreads();   // publish s_bndp (wave 0) to all waves

    const int row = blockIdx.x * WAVES_PER_BLOCK + wave;
    if (row < nrows) {
        const float4* xr = (const float4*)(x + (size_t)row * FDIM);
        float4 v0 = xr[lane];
        float4 v1 = xr[64 + lane];
        float4 v2 = xr[128 + lane];
        float4 v3 = xr[192 + lane];

        float vals[16] = {v0.x, v0.y, v0.z, v0.w, v1.x, v1.y, v1.z, v1.w,
                          v2.x, v2.y, v2.z, v2.w, v3.x, v3.y, v3.z, v3.w};
        #pragma unroll
        for (int e = 0; e < 16; ++e) {
            float xv = vals[e];
            // t-space: ideal boundary i sits exactly at t = i+1 (7.75*(8/62) == 1)
            float t  = fmaf(xv, 7.75f, 32.0f);
            float ft = floorf(t);
            int   j  = (int)ft;
            float frac = t - ft;            // always in [0,1)
            // rare path: near a bin edge (analytic result uncertain) or out of range
            if (__builtin_expect(frac < EPS || frac > 1.0f - EPS ||
                                 (unsigned)j > 63u, 0)) {
                j = j < 0 ? 0 : (j > NB ? NB : j);
                while (s_bndp[j + 1] <= xv) ++j;   // +inf sentinel terminates
                while (s_bndp[j] > xv) --j;        // -inf sentinel terminates
            }
            atomicAdd(&s_hist[wave][grp][j ^ gx], 1u);
        }

        // merge: only this wave's own sub-histograms -> no barrier needed
        // (compiler inserts lgkmcnt wait on the dependent reads)
        unsigned int total = 0u;
        #pragma unroll
        for (int g = 0; g < SUBHIST; ++g)
            total += s_hist[wave][g][lane ^ (g << 2)];
        out[(size_t)row * NBINS + lane] = (float)total * (1.0f / (float)FDIM);
    }
}

extern "C" void kernel_launch(void* const* d_in, const int* in_sizes, int n_in,
                              void* d_out, int out_size, void* d_ws, size_t ws_size,
                              hipStream_t stream) {
    const float* x   = (const float*)d_in[0];
    const float* bnd = (const float*)d_in[1];
    float* out = (float*)d_out;

    const int nrows = in_sizes[0] / FDIM;               // 16384
    const int grid  = (nrows + WAVES_PER_BLOCK - 1) / WAVES_PER_BLOCK;  // 4096

    dist_tok_kernel<<<grid, 256, 0, stream>>>(x, bnd, out, nrows);
}